// Round 2
// baseline (378.888 us; speedup 1.0000x reference)
//
#include <hip/hip_runtime.h>

typedef _Float16 half8 __attribute__((ext_vector_type(8)));
typedef float floatx4 __attribute__((ext_vector_type(4)));

constexpr int IN_F  = 8192;
constexpr int OUT_F = 8192;
constexpr int NCOL  = 16;

constexpr int CHUNKS  = 32;                      // K-split factor
constexpr int CHUNK_K = IN_F / CHUNKS;           // 256
constexpr int STEPS   = CHUNK_K / 32;            // 8 MFMA k-steps per chunk
constexpr int RB      = 4;                       // 16-row tiles per wave
constexpr int WPB     = 4;                       // waves per block (256 thr)
constexpr int ROWS_PER_WAVE = RB * 16;           // 64
constexpr int RGROUPS = OUT_F / ROWS_PER_WAVE;   // 128
constexpr int NBLOCKS = CHUNKS * RGROUPS / WPB;  // 1024
constexpr size_t PART_STRIDE = (size_t)OUT_F * NCOL;  // floats per chunk-partial

// D = W @ x. W as MFMA A-operand, x as B, fp32 acc. K split across CHUNKS;
// partials land in d_ws (no atomics), reduce kernel folds + scales into out.
// Layouts (gfx950, HW-verified): A[m=lane&15][k=quad*8+j],
// B[k=quad*8+j][n=lane&15], C/D: col=lane&15, row=quad*4+reg.
__global__ __launch_bounds__(256, 4)
void lq_mfma_kernel(const float* __restrict__ x,
                    const void* __restrict__ wraw,
                    float* __restrict__ part)
{
    const int tid   = threadIdx.x;
    const int lane  = tid & 63;
    const int wv    = tid >> 6;
    const int W     = blockIdx.x * WPB + wv;     // 0..4095
    const int chunk = W & (CHUNKS - 1);          // k-chunk id
    const int rg    = W / CHUNKS;                // row-group id (64 rows)
    const int k0    = chunk * CHUNK_K;
    const int m     = lane & 15;                 // A row-in-tile == C col
    const int quad  = lane >> 4;

    // ---- dtype probe: int32-materialized weights vs raw int8 (wave-uniform) ----
    const int* wi = (const int*)wraw;
    bool w_is_i32 = true;
    #pragma unroll
    for (int i = 0; i < 16; ++i) {
        int v = wi[i];
        w_is_i32 = w_is_i32 && (v >= -128) && (v <= 127);
    }

    // ---- B fragments: x resident in 32 VGPRs for the whole kernel ----
    half8 bf[STEPS];
    #pragma unroll
    for (int st = 0; st < STEPS; ++st) {
        #pragma unroll
        for (int j = 0; j < 8; ++j) {
            const int k = k0 + st * 32 + quad * 8 + j;
            bf[st][j] = (_Float16)x[k * NCOL + m];
        }
    }

    float* pbase = part + (size_t)chunk * PART_STRIDE;

    if (w_is_i32) {
        // ---- path A: weights materialized as int32 (268 MB stream) ----
        const int* wp = (const int*)wraw;
        #pragma unroll 1
        for (int r = 0; r < RB; ++r) {
            const int row = rg * ROWS_PER_WAVE + r * 16 + m;
            const uint4* wrow = (const uint4*)(wp + (size_t)row * IN_F + k0 + quad * 8);
            // stage the whole row slice first: 16 dwordx4 loads in flight
            uint4 raw[2 * STEPS];
            #pragma unroll
            for (int st = 0; st < STEPS; ++st) {
                raw[2 * st]     = wrow[8 * st];      // +st*32 ints
                raw[2 * st + 1] = wrow[8 * st + 1];
            }
            floatx4 acc = {0.f, 0.f, 0.f, 0.f};
            #pragma unroll
            for (int st = 0; st < STEPS; ++st) {
                half8 af;
                const int* p0 = (const int*)&raw[2 * st];
                #pragma unroll
                for (int j = 0; j < 8; ++j)
                    af[j] = (_Float16)p0[j];
                acc = __builtin_amdgcn_mfma_f32_16x16x32_f16(af, bf[st], acc, 0, 0, 0);
            }
            const int orow = rg * ROWS_PER_WAVE + r * 16 + quad * 4;
            #pragma unroll
            for (int g = 0; g < 4; ++g)
                pbase[(size_t)(orow + g) * NCOL + m] = acc[g];
        }
    } else {
        // ---- path B: raw int8 weights (64 MB stream) ----
        const signed char* wp = (const signed char*)wraw;
        #pragma unroll 1
        for (int r = 0; r < RB; ++r) {
            const int row = rg * ROWS_PER_WAVE + r * 16 + m;
            const uint2* wrow = (const uint2*)(wp + (size_t)row * IN_F + k0 + quad * 8);
            uint2 raw[STEPS];
            #pragma unroll
            for (int st = 0; st < STEPS; ++st)
                raw[st] = wrow[4 * st];              // +st*32 bytes
            floatx4 acc = {0.f, 0.f, 0.f, 0.f};
            #pragma unroll
            for (int st = 0; st < STEPS; ++st) {
                half8 af;
                #pragma unroll
                for (int j = 0; j < 4; ++j) {
                    af[j]     = (_Float16)(int)(signed char)(raw[st].x >> (8 * j));
                    af[j + 4] = (_Float16)(int)(signed char)(raw[st].y >> (8 * j));
                }
                acc = __builtin_amdgcn_mfma_f32_16x16x32_f16(af, bf[st], acc, 0, 0, 0);
            }
            const int orow = rg * ROWS_PER_WAVE + r * 16 + quad * 4;
            #pragma unroll
            for (int g = 0; g < 4; ++g)
                pbase[(size_t)(orow + g) * NCOL + m] = acc[g];
        }
    }
}

// out[i] = scaler * sum_c part[c][i], vectorized float4. Overwrites all of out.
__global__ __launch_bounds__(256)
void lq_reduce_kernel(const float* __restrict__ part,
                      const float* __restrict__ scaler,
                      float* __restrict__ out)
{
    const int i = blockIdx.x * blockDim.x + threadIdx.x;   // over 32768 float4s
    const float4* p = (const float4*)part;
    const int stride = (int)(PART_STRIDE / 4);
    float4 a = p[i];
    #pragma unroll
    for (int c = 1; c < CHUNKS; ++c) {
        float4 v = p[(size_t)c * stride + i];
        a.x += v.x; a.y += v.y; a.z += v.z; a.w += v.w;
    }
    const float s = *scaler;
    float4 r = {a.x * s, a.y * s, a.z * s, a.w * s};
    ((float4*)out)[i] = r;
}

extern "C" void kernel_launch(void* const* d_in, const int* in_sizes, int n_in,
                              void* d_out, int out_size, void* d_ws, size_t ws_size,
                              hipStream_t stream)
{
    const float* x      = (const float*)d_in[0];
    const void*  w      = d_in[1];
    const float* scaler = (const float*)d_in[2];
    float*       out    = (float*)d_out;
    float*       part   = (float*)d_ws;   // 32 * 512 KB = 16 MB << ws_size

    lq_mfma_kernel<<<NBLOCKS, 256, 0, stream>>>(x, w, part);
    lq_reduce_kernel<<<(OUT_F * NCOL / 4) / 256, 256, 0, stream>>>(part, scaler, out);
}

// Round 3
// 376.955 us; speedup vs baseline: 1.0051x; 1.0051x over previous
//
#include <hip/hip_runtime.h>
#include <stdint.h>

typedef _Float16 half8 __attribute__((ext_vector_type(8)));
typedef float floatx4 __attribute__((ext_vector_type(4)));

#define AS1 __attribute__((address_space(1)))
#define AS3 __attribute__((address_space(3)))

constexpr int IN_F  = 8192;
constexpr int OUT_F = 8192;
constexpr int NCOL  = 16;

constexpr int CHUNKS  = 32;                       // K-split
constexpr int CHUNK_K = IN_F / CHUNKS;            // 256 k-ints per wave
constexpr int RB      = 8;                        // 16-row tiles per wave
constexpr int WPB     = 4;                        // waves per block
constexpr int RGROUPS = OUT_F / (RB * 16);        // 64
constexpr int NBLOCKS = CHUNKS * RGROUPS / WPB;   // 512 = exactly 2 blocks/CU
constexpr size_t PART_STRIDE = (size_t)OUT_F * NCOL;

// Weight stream goes HBM -> (global_load_lds, no VGPR round-trip) -> per-wave
// private LDS double-buffer -> ds_read_b128 -> cvt f16 -> MFMA. No barriers:
// each wave owns its buffers; pipeline via explicit s_waitcnt vmcnt(N).
// LDS half-tile layout (int32 path): [chunk16B c:0..31][row:0..15][16B],
// written by 8 global_load_lds (lane l: row=l&15, c=4i+(l>>4)), read as
// b128 at c*256 + row*16. MFMA layouts as verified in rounds 1-2.
__global__ __launch_bounds__(256, 2)
void lq_mfma_kernel(const float* __restrict__ x,
                    const void* __restrict__ wraw,
                    float* __restrict__ part)
{
    __shared__ uint4 smem[WPB * 2 * 512];         // 4 waves * 2 * 8KB = 64KB

    const int tid  = threadIdx.x;
    const int lane = tid & 63;
    const int wv   = tid >> 6;
    const int W    = blockIdx.x * WPB + wv;       // 0..2047
    const int chunk= W & (CHUNKS - 1);
    const int rg   = W / CHUNKS;                  // 0..63
    const int k0   = chunk * CHUNK_K;             // in k-elements
    const int m    = lane & 15;                   // row-in-tile == C col
    const int q    = lane >> 4;                   // quad
    const int rowTop = rg * (RB * 16);

    // ---- dtype probe: int32-materialized vs raw int8 (wave-uniform) ----
    const int* wi = (const int*)wraw;
    bool w_is_i32 = true;
    #pragma unroll
    for (int i = 0; i < 16; ++i) {
        int v = wi[i];
        w_is_i32 = w_is_i32 && (v >= -128) && (v <= 127);
    }

    // ---- B fragments: x resident in 32 VGPRs ----
    half8 bf[8];
    #pragma unroll
    for (int sk = 0; sk < 8; ++sk)
        #pragma unroll
        for (int j = 0; j < 8; ++j)
            bf[sk][j] = (_Float16)x[(k0 + sk * 32 + q * 8 + j) * NCOL + m];

    char* lds_wave = (char*)smem + wv * 16384;
    const uint32_t lbase = (uint32_t)(uintptr_t)(AS3 char*)lds_wave;
    float* pbase = part + (size_t)chunk * PART_STRIDE;

    if (w_is_i32) {
        // ================= int32 weights (268 MB stream) =================
        const int* wp = (const int*)wraw;
        const int* g0 = wp + (size_t)(rowTop + m) * IN_F + k0 + q * 4;

        auto issue = [&](int th) {                 // 8 x 16B/lane -> 8KB
            const int r = th >> 1, h = th & 1, p = th & 1;
            char* ldst = lds_wave + p * 8192;
            const int* g = g0 + (size_t)r * 16 * IN_F + h * 128;
            #pragma unroll
            for (int i = 0; i < 8; ++i)
                __builtin_amdgcn_global_load_lds(
                    (AS1 void*)(g + i * 16),
                    (AS3 void*)(ldst + i * 1024), 16, 0, 0);
        };

        issue(0);
        floatx4 acc = {0.f, 0.f, 0.f, 0.f};
        #pragma unroll 2
        for (int th = 0; th < RB * 2; ++th) {
            if (th + 1 < RB * 2) {
                issue(th + 1);
                asm volatile("s_waitcnt vmcnt(8)" ::: "memory");
            } else {
                asm volatile("s_waitcnt vmcnt(0)" ::: "memory");
            }
            const int h = th & 1, p = th & 1;
            const uint32_t a0 = lbase + p * 8192 + (uint32_t)(2 * q) * 256
                              + (uint32_t)m * 16;
            uint4 r0, r1, r2, r3, r4, r5, r6, r7;
            asm volatile(
                "ds_read_b128 %0, %8 offset:0\n\t"
                "ds_read_b128 %1, %8 offset:256\n\t"
                "ds_read_b128 %2, %8 offset:2048\n\t"
                "ds_read_b128 %3, %8 offset:2304\n\t"
                "ds_read_b128 %4, %8 offset:4096\n\t"
                "ds_read_b128 %5, %8 offset:4352\n\t"
                "ds_read_b128 %6, %8 offset:6144\n\t"
                "ds_read_b128 %7, %8 offset:6400\n\t"
                "s_waitcnt lgkmcnt(0)"
                : "=v"(r0), "=v"(r1), "=v"(r2), "=v"(r3),
                  "=v"(r4), "=v"(r5), "=v"(r6), "=v"(r7)
                : "v"(a0) : "memory");
            const uint4 rr[8] = {r0, r1, r2, r3, r4, r5, r6, r7};
            #pragma unroll
            for (int s = 0; s < 4; ++s) {
                half8 af;
                const int* pa = (const int*)&rr[2 * s];
                #pragma unroll
                for (int j = 0; j < 8; ++j)
                    af[j] = (_Float16)pa[j];
                acc = __builtin_amdgcn_mfma_f32_16x16x32_f16(af, bf[h * 4 + s],
                                                             acc, 0, 0, 0);
            }
            if (h == 1) {
                const int orow = rowTop + (th >> 1) * 16 + q * 4;
                #pragma unroll
                for (int g = 0; g < 4; ++g)
                    pbase[(size_t)(orow + g) * NCOL + m] = acc[g];
                acc = (floatx4){0.f, 0.f, 0.f, 0.f};
            }
        }
    } else {
        // ================= raw int8 weights (64 MB stream) ===============
        const int8_t* wp = (const int8_t*)wraw;
        const int8_t* g0 = wp + (size_t)(rowTop + m) * IN_F + k0 + q * 16;

        auto issue = [&](int th) {                 // 2 x 16B/lane -> 2KB
            const int r = th >> 1, h = th & 1, p = th & 1;
            char* ldst = lds_wave + p * 8192;
            const int8_t* g = g0 + (size_t)r * 16 * IN_F + h * 128;
            #pragma unroll
            for (int i = 0; i < 2; ++i)
                __builtin_amdgcn_global_load_lds(
                    (AS1 void*)(g + i * 64),
                    (AS3 void*)(ldst + i * 1024), 16, 0, 0);
        };

        issue(0);
        floatx4 acc = {0.f, 0.f, 0.f, 0.f};
        #pragma unroll 2
        for (int th = 0; th < RB * 2; ++th) {
            if (th + 1 < RB * 2) {
                issue(th + 1);
                asm volatile("s_waitcnt vmcnt(2)" ::: "memory");
            } else {
                asm volatile("s_waitcnt vmcnt(0)" ::: "memory");
            }
            const int h = th & 1, p = th & 1;
            const uint32_t a0 = lbase + p * 8192 + (uint32_t)(q >> 1) * 256
                              + (uint32_t)m * 16 + (uint32_t)(q & 1) * 8;
            uint2 d0, d1, d2, d3;
            asm volatile(
                "ds_read_b64 %0, %4 offset:0\n\t"
                "ds_read_b64 %1, %4 offset:512\n\t"
                "ds_read_b64 %2, %4 offset:1024\n\t"
                "ds_read_b64 %3, %4 offset:1536\n\t"
                "s_waitcnt lgkmcnt(0)"
                : "=v"(d0), "=v"(d1), "=v"(d2), "=v"(d3)
                : "v"(a0) : "memory");
            const uint2 dd[4] = {d0, d1, d2, d3};
            #pragma unroll
            for (int s = 0; s < 4; ++s) {
                half8 af;
                #pragma unroll
                for (int j = 0; j < 4; ++j) {
                    af[j]     = (_Float16)(int)(int8_t)(dd[s].x >> (8 * j));
                    af[j + 4] = (_Float16)(int)(int8_t)(dd[s].y >> (8 * j));
                }
                acc = __builtin_amdgcn_mfma_f32_16x16x32_f16(af, bf[h * 4 + s],
                                                             acc, 0, 0, 0);
            }
            if (h == 1) {
                const int orow = rowTop + (th >> 1) * 16 + q * 4;
                #pragma unroll
                for (int g = 0; g < 4; ++g)
                    pbase[(size_t)(orow + g) * NCOL + m] = acc[g];
                acc = (floatx4){0.f, 0.f, 0.f, 0.f};
            }
        }
    }
}

// out[i] = scaler * sum_c part[c][i]
__global__ __launch_bounds__(256)
void lq_reduce_kernel(const float* __restrict__ part,
                      const float* __restrict__ scaler,
                      float* __restrict__ out)
{
    const int i = blockIdx.x * blockDim.x + threadIdx.x;   // 32768 float4s
    const float4* p = (const float4*)part;
    const int stride = (int)(PART_STRIDE / 4);
    float4 a = p[i];
    #pragma unroll
    for (int c = 1; c < CHUNKS; ++c) {
        float4 v = p[(size_t)c * stride + i];
        a.x += v.x; a.y += v.y; a.z += v.z; a.w += v.w;
    }
    const float s = *scaler;
    float4 r = {a.x * s, a.y * s, a.z * s, a.w * s};
    ((float4*)out)[i] = r;
}

extern "C" void kernel_launch(void* const* d_in, const int* in_sizes, int n_in,
                              void* d_out, int out_size, void* d_ws, size_t ws_size,
                              hipStream_t stream)
{
    const float* x      = (const float*)d_in[0];
    const void*  w      = d_in[1];
    const float* scaler = (const float*)d_in[2];
    float*       out    = (float*)d_out;
    float*       part   = (float*)d_ws;   // 32 * 512KB = 16MB << ws_size

    lq_mfma_kernel<<<NBLOCKS, 256, 0, stream>>>(x, w, part);
    lq_reduce_kernel<<<(OUT_F * NCOL / 4) / 256, 256, 0, stream>>>(part, scaler, out);
}